// Round 8
// baseline (378.774 us; speedup 1.0000x reference)
//
#include <hip/hip_runtime.h>
#include <stdint.h>
#include <math.h>

// ---------------------------------------------------------------------------
// FlashNeoxAttention: qkv = h@Wqkv+b ; rotary(q,k) ; causal flash attn ; @Wd+b
// T=4096 (B=4 x S=1024), H=16 heads x D=128, ROT=16 (first 32 dims rotated)
// R11: (a) gemm_qkv reverted to the R8 drain calendar (120.7us, passed 2x;
//      R10's counted gates were a measured null at 124us). (b) attn: V-staging
//      DROPPED (m169 lesson: V is L2-resident at S=1024; staging is pure
//      overhead). PV reads V-fragments directly from global vT_ws; 16 loads
//      issued before QK^T (~600cyc cover), K prefetch issued after them so
//      the counted vmcnt wait for V leaves K in flight. -32KB LDS -> 3
//      blocks/CU. K path / softmax / P layout unchanged.
// ---------------------------------------------------------------------------

typedef __attribute__((ext_vector_type(8))) short short8;   // 8 x bf16 (4 VGPR)
typedef __attribute__((ext_vector_type(4))) float f32x4;    // MFMA C/D frag

__device__ __forceinline__ unsigned short f2b(float f) {
  union { float f; unsigned int i; } x; x.f = f;
  unsigned int r = x.i + 0x7FFFu + ((x.i >> 16) & 1u);  // round-nearest-even
  return (unsigned short)(r >> 16);
}

#define GAS(p) ((const __attribute__((address_space(1))) void*)(p))
#define LAS(p) ((__attribute__((address_space(3))) void*)(p))

// ---------------------------------------------------------------------------
// f32 -> bf16 convert, 8 elems/thread.
// ---------------------------------------------------------------------------
__global__ __launch_bounds__(256) void convert_kernel(
    const float* __restrict__ src, unsigned short* __restrict__ dst) {
  const size_t base = ((size_t)blockIdx.x * 256 + threadIdx.x) * 8;
  float4 v0 = *(const float4*)&src[base];
  float4 v1 = *(const float4*)&src[base + 4];
  unsigned short t8[8] = {f2b(v0.x), f2b(v0.y), f2b(v0.z), f2b(v0.w),
                          f2b(v1.x), f2b(v1.y), f2b(v1.z), f2b(v1.w)};
  *(uint4*)&dst[base] = *(uint4*)t8;
}

// ---------------------------------------------------------------------------
// Transpose+convert W f32 [K][N] -> WT bf16 [N][K], 64x64 tiles, padded LDS.
// ---------------------------------------------------------------------------
__global__ __launch_bounds__(256) void transpose_convert_kernel(
    const float* __restrict__ src, unsigned short* __restrict__ dst,
    const int K, const int N) {
  __shared__ __align__(16) unsigned short tile[64][72];  // +8 pad
  const int n0 = blockIdx.x * 64, k0 = blockIdx.y * 64;
  const int tid = threadIdx.x;
#pragma unroll
  for (int p = 0; p < 2; ++p) {
    const int idx = p * 256 + tid;
    const int r = idx >> 3, c8 = idx & 7;
    const float* sp = &src[(size_t)(k0 + r) * N + n0 + c8 * 8];
    float4 v0 = *(const float4*)sp;
    float4 v1 = *(const float4*)(sp + 4);
    unsigned short t8[8] = {f2b(v0.x), f2b(v0.y), f2b(v0.z), f2b(v0.w),
                            f2b(v1.x), f2b(v1.y), f2b(v1.z), f2b(v1.w)};
    *(uint4*)&tile[r][c8 * 8] = *(uint4*)t8;
  }
  __syncthreads();
#pragma unroll
  for (int p = 0; p < 2; ++p) {
    const int idx = p * 256 + tid;
    const int r = idx >> 3, c8 = idx & 7;
    unsigned short out[8];
#pragma unroll
    for (int j = 0; j < 8; ++j) out[j] = tile[c8 * 8 + j][r];
    *(uint4*)&dst[(size_t)(n0 + r) * K + k0 + c8 * 8] = *(uint4*)out;
  }
}

// ---------------------------------------------------------------------------
// gemm_qkv (R8-proven): 128(M) x 384(N) tile, BK=64, 8 waves (2Mx4N, wave
// 64x96), 3 phases/K-tile, grid 32x16 = 512 blocks = 2 exact rounds.
// Units: A(128x64), B0,B1,B2(128x64). LDS elems:
//   A: buf*8192 (0..16384); B: 16384 + buf*24576 + u*8192. Total 128 KiB.
// RACE-SAFE calendar: every phase's reads span ALL B units (wave wn reads
// rows wn*96+..), so tile T must be fully resident before T p1. Stages:
//   p1: A,B0,B1(T+1)->nb (6 loads); p2: B2(T+1)->nb (2 loads);
//   p3: vmcnt(0) DRAIN (all tile T+1 resident) + barrier.
// ---------------------------------------------------------------------------

#define QSTAGE(SRC, R0, KT, LDSOFF)                                           \
  do {                                                                        \
    _Pragma("unroll") for (int p_ = 0; p_ < 2; ++p_) {                        \
      const int cb_ = w * 2 + p_;                                             \
      __builtin_amdgcn_global_load_lds(                                       \
          GAS((SRC) + (size_t)((R0) + cb_ * 8 + rl) * 2048 + (KT) + cg * 8),  \
          LAS(smem + (LDSOFF) + cb_ * 512), 16, 0, 0);                        \
    }                                                                         \
  } while (0)

#define QLDA                                                                  \
  do {                                                                        \
    _Pragma("unroll") for (int mf_ = 0; mf_ < 4; ++mf_) {                     \
      const int r_ = wm * 64 + mf_ * 16 + l15;                                \
      const unsigned short* rp_ = smem + abo + r_ * 64;                       \
      _Pragma("unroll") for (int ks_ = 0; ks_ < 2; ++ks_)                     \
        af[mf_][ks_] = *(const short8*)&rp_[((ks_ * 4 + g) ^ (r_ & 7)) * 8];  \
    }                                                                         \
  } while (0)

#define QLDB(NH)                                                              \
  do {                                                                        \
    _Pragma("unroll") for (int nf_ = 0; nf_ < 2; ++nf_) {                     \
      const int r_ = wn * 96 + (NH) * 32 + nf_ * 16 + l15;                    \
      const unsigned short* rp_ = smem + 16384 + bbo + r_ * 64;               \
      _Pragma("unroll") for (int ks_ = 0; ks_ < 2; ++ks_)                     \
        bfr[nf_][ks_] = *(const short8*)&rp_[((ks_ * 4 + g) ^ (r_ & 7)) * 8]; \
    }                                                                         \
  } while (0)

#define QMMA(NH)                                                              \
  do {                                                                        \
    __builtin_amdgcn_s_setprio(1);                                            \
    _Pragma("unroll") for (int mf_ = 0; mf_ < 4; ++mf_)                       \
    _Pragma("unroll") for (int nf_ = 0; nf_ < 2; ++nf_)                       \
    _Pragma("unroll") for (int ks_ = 0; ks_ < 2; ++ks_)                       \
      acc[mf_][(NH) * 2 + nf_] = __builtin_amdgcn_mfma_f32_16x16x32_bf16(     \
          af[mf_][ks_], bfr[nf_][ks_], acc[mf_][(NH) * 2 + nf_], 0, 0, 0);    \
    __builtin_amdgcn_s_setprio(0);                                            \
    __builtin_amdgcn_sched_barrier(0);                                        \
  } while (0)

__global__ __launch_bounds__(512, 2) void gemm_qkv_kernel(
    const unsigned short* __restrict__ A, const unsigned short* __restrict__ BT,
    const float* __restrict__ bias,
    const float* __restrict__ cosp, const float* __restrict__ sinp,
    unsigned short* __restrict__ q_ws, unsigned short* __restrict__ k_ws,
    unsigned short* __restrict__ vT_ws) {
  extern __shared__ unsigned short smem[];  // 65536 elems = 128 KiB
  const int NT = 32;

  const int tid = threadIdx.x;
  const int lane = tid & 63;
  const int w = tid >> 6;            // wave 0..7
  const int wm = w >> 2, wn = w & 3; // 2M x 4N; wave tile 64 x 96
  const int l15 = lane & 15, g = lane >> 4;
  const int rl = lane >> 3;                // staging: row within 8-row chunk
  const int cg = (lane & 7) ^ rl;          // pre-swizzled global 16B-chunk

  // bijective XCD swizzle (512 % 8 == 0)
  const int nbx = gridDim.x;               // 16 (n tiles)
  const int cpx = (nbx * gridDim.y) >> 3;
  const int orig = blockIdx.y * nbx + blockIdx.x;
  const int wgid = (orig & 7) * cpx + (orig >> 3);
  const int bx = wgid % nbx, by = wgid / nbx;
  const int m0 = by * 128, n0 = bx * 384;

  f32x4 acc[4][6];
#pragma unroll
  for (int i = 0; i < 4; ++i)
#pragma unroll
    for (int j = 0; j < 6; ++j) acc[i][j] = (f32x4){0.f, 0.f, 0.f, 0.f};

  // prologue: stage tile 0 (A, B0, B1, B2) into buf 0, then DRAIN.
  QSTAGE(A, m0, 0, 0);
  QSTAGE(BT, n0, 0, 16384);
  QSTAGE(BT, n0 + 128, 0, 24576);
  QSTAGE(BT, n0 + 256, 0, 32768);
  asm volatile("s_waitcnt vmcnt(0)" ::: "memory");  // tile0 resident
  __builtin_amdgcn_s_barrier();

  short8 af[4][2], bfr[2][2];

  for (int T = 0; T < NT; ++T) {
    const int buf = T & 1, nb = buf ^ 1;
    const int abo = buf * 8192;
    const int bbo = buf * 24576;
    const int nabo = nb * 8192;
    const int nbbo = nb * 24576;
    const int ktn = (T + 1) << 6;
    const bool pf1 = (T + 1 < NT);

    // ---- p1: stage A,B0,B1(T+1); read A,B_nf01(T) ----
    if (pf1) {
      QSTAGE(A, m0, ktn, nabo);
      QSTAGE(BT, n0, ktn, 16384 + nbbo);
      QSTAGE(BT, n0 + 128, ktn, 24576 + nbbo);
    }
    QLDA;
    QLDB(0);
    __builtin_amdgcn_s_barrier();
    asm volatile("s_waitcnt lgkmcnt(0)" ::: "memory");
    __builtin_amdgcn_sched_barrier(0);
    QMMA(0);
    __builtin_amdgcn_s_barrier();

    // ---- p2: stage B2(T+1); read B_nf23(T) ----
    if (pf1) QSTAGE(BT, n0 + 256, ktn, 32768 + nbbo);
    QLDB(1);
    __builtin_amdgcn_s_barrier();
    asm volatile("s_waitcnt lgkmcnt(0)" ::: "memory");
    __builtin_amdgcn_sched_barrier(0);
    QMMA(1);
    __builtin_amdgcn_s_barrier();

    // ---- p3: DRAIN (tile T+1 fully resident); read B_nf45(T) ----
    QLDB(2);
    asm volatile("s_waitcnt vmcnt(0)" ::: "memory");  // retire tile T+1 (all)
    __builtin_amdgcn_s_barrier();
    asm volatile("s_waitcnt lgkmcnt(0)" ::: "memory");
    __builtin_amdgcn_sched_barrier(0);
    QMMA(2);
    __builtin_amdgcn_s_barrier();
  }

  // ---- epilogue: bias (cols gc = n0 + wn*96 + nf*16 + l15) ----
  float bv[6];
#pragma unroll
  for (int nf = 0; nf < 6; ++nf) bv[nf] = bias[n0 + wn * 96 + nf * 16 + l15];
#pragma unroll
  for (int mi = 0; mi < 4; ++mi)
#pragma unroll
    for (int nf = 0; nf < 6; ++nf)
#pragma unroll
      for (int jj = 0; jj < 4; ++jj) acc[mi][nf][jj] += bv[nf];

  // ---- rotary: group nf has head-local idx hg=((6*wn+nf)&7); rotate pair
  //      (nf,nf+1) where hg==0, only for q/k col-blocks. Never splits a wave.
#pragma unroll
  for (int nf = 0; nf < 5; ++nf) {
    if (((6 * wn + nf) & 7) == 0) {
      const int jb = (wn * 96 + nf * 16) >> 7;          // col-block 0..2
      const int whichj = (n0 + jb * 128) >> 11;          // 0=q 1=k 2=v
      if (whichj < 2) {
#pragma unroll
        for (int mi = 0; mi < 4; ++mi)
#pragma unroll
          for (int jj = 0; jj < 4; ++jj) {
            const int t = m0 + wm * 64 + mi * 16 + g * 4 + jj;
            const float c = cosp[t * 16 + l15];
            const float s = sinp[t * 16 + l15];
            const float a1 = acc[mi][nf][jj], a2 = acc[mi][nf + 1][jj];
            acc[mi][nf][jj] = a1 * c - a2 * s;
            acc[mi][nf + 1][jj] = a1 * s + a2 * c;
          }
      }
    }
  }

  // ---- write C into 3 per-head LDS sub-tiles [128][136] (v transposed) ----
  const int b = m0 >> 10, s0v = m0 & 1023;
#pragma unroll
  for (int mi = 0; mi < 4; ++mi)
#pragma unroll
    for (int nf = 0; nf < 6; ++nf)
#pragma unroll
      for (int jj = 0; jj < 4; ++jj) {
        const int r = wm * 64 + mi * 16 + g * 4 + jj;    // token-local 0..127
        const int gc = wn * 96 + nf * 16 + l15;          // tile col 0..383
        const int jb = gc >> 7, lc = gc & 127;
        const int whichj = (n0 + jb * 128) >> 11;
        const unsigned short hv = f2b(acc[mi][nf][jj]);
        if (whichj < 2) smem[jb * 17408 + r * 136 + lc] = hv;
        else            smem[jb * 17408 + lc * 136 + r] = hv;
      }
  __syncthreads();

  // ---- flush sub-tiles, per-block q/k/v routing ----
#pragma unroll
  for (int jb = 0; jb < 3; ++jb) {
    const int gcb = n0 + jb * 128;
    const int whichj = gcb >> 11;
    const int head = (gcb >> 7) & 15;
#pragma unroll
    for (int p4 = 0; p4 < 4; ++p4) {
      const int idx = p4 * 512 + tid;
      const int rr = idx >> 4, c8 = idx & 15;
      uint4 v = *(const uint4*)&smem[jb * 17408 + rr * 136 + c8 * 8];
      unsigned short* dp;
      if (whichj == 0)
        dp = q_ws + ((size_t)(b * 16 + head) * 1024 + s0v + rr) * 128 + c8 * 8;
      else if (whichj == 1)
        dp = k_ws + ((size_t)(b * 16 + head) * 1024 + s0v + rr) * 128 + c8 * 8;
      else  // v: sub-tile row rr = head-dim d, cols = local tokens
        dp = vT_ws + ((size_t)(b * 16 + head) * 128 + rr) * 1024 + s0v + c8 * 8;
      *(uint4*)dp = v;
    }
  }
}

// ---------------------------------------------------------------------------
// gemm_out: C[4096][2048] f32 = A @ WdT^T + bias. Tile 128(M) x 256(N), BK=64,
// grid 8x32 = 256 blocks (exactly one full dispatch round). 8 waves (2Mx4N),
// wave out 64x64, 2 phases/K-tile (nf01 / nf23), 16 MFMA each. (R5 form.)
// ---------------------------------------------------------------------------

#define M1_STG(SRC, R0, KT, LB)                                               \
  __builtin_amdgcn_global_load_lds(                                           \
      GAS((SRC) + (size_t)((R0) + w * 8 + rl) * 2048 + (KT) + cg * 8),        \
      LAS(smem + (LB) + w * 512), 16, 0, 0)

#define M1_LDA                                                                \
  do {                                                                        \
    _Pragma("unroll") for (int mf_ = 0; mf_ < 4; ++mf_) {                     \
      const int r_ = wm * 64 + mf_ * 16 + l15;                                \
      const unsigned short* rp_ = smem + abo + r_ * 64;                       \
      _Pragma("unroll") for (int ks_ = 0; ks_ < 2; ++ks_)                     \
        af[mf_][ks_] = *(const short8*)&rp_[((ks_ * 4 + g) ^ (r_ & 7)) * 8];  \
    }                                                                         \
  } while (0)

#define M1_LDB(NH)                                                            \
  do {                                                                        \
    _Pragma("unroll") for (int nf_ = 0; nf_ < 2; ++nf_) {                     \
      const int r_ = wn * 64 + (NH) * 32 + nf_ * 16 + l15;                    \
      const unsigned short* rp_ = smem + bbo + r_ * 64;                       \
      _Pragma("unroll") for (int ks_ = 0; ks_ < 2; ++ks_)                     \
        bfr[nf_][ks_] = *(const short8*)&rp_[((ks_ * 4 + g) ^ (r_ & 7)) * 8]; \
    }                                                                         \
  } while (0)

#define M1_MMA(NH)                                                            \
  do {                                                                        \
    __builtin_amdgcn_s_setprio(1);                                            \
    _Pragma("unroll") for (int mf_ = 0; mf_ < 4; ++mf_)                       \
    _Pragma("unroll") for (int nf_ = 0; nf_ < 2; ++nf_)                       \
    _Pragma("unroll") for (int ks_ = 0; ks_ < 2; ++ks_)                       \
      acc[mf_][(NH) * 2 + nf_] = __builtin_amdgcn_mfma_f32_16x16x32_bf16(     \
          af[mf_][ks_], bfr[nf_][ks_], acc[mf_][(NH) * 2 + nf_], 0, 0, 0);    \
    __builtin_amdgcn_s_setprio(0);                                            \
    __builtin_amdgcn_sched_barrier(0);                                        \
  } while (0)

__global__ __launch_bounds__(512, 2) void gemm_out_kernel(
    const unsigned short* __restrict__ A, const unsigned short* __restrict__ BT,
    const float* __restrict__ bias, float* __restrict__ outp) {
  extern __shared__ unsigned short smem[];  // 49152 elems = 96 KiB
  const int NT = 32;

  const int tid = threadIdx.x;
  const int lane = tid & 63;
  const int w = tid >> 6;
  const int wm = w >> 2, wn = w & 3;   // 2M x 4N, wave out 64x64
  const int l15 = lane & 15, g = lane >> 4;
  const int rl = lane >> 3;
  const int cg = (lane & 7) ^ rl;

  // bijective XCD swizzle (256 % 8 == 0)
  const int nbx = gridDim.x;
  const int cpx = (nbx * gridDim.y) >> 3;
  const int orig = blockIdx.y * nbx + blockIdx.x;
  const int wgid = (orig & 7) * cpx + (orig >> 3);
  const int bx = wgid % nbx, by = wgid / nbx;
  const int m0 = by * 128, n0 = bx * 256;

  f32x4 acc[4][4];
#pragma unroll
  for (int i = 0; i < 4; ++i)
#pragma unroll
    for (int j = 0; j < 4; ++j) acc[i][j] = (f32x4){0.f, 0.f, 0.f, 0.f};

  // prologue: A01(0), BQ0..3(0), A01(1); gate retires tile0 (6 loads)
  M1_STG(A, m0, 0, 0);
  M1_STG(A, m0 + 64, 0, 4096);
  M1_STG(BT, n0, 0, 16384);
  M1_STG(BT, n0 + 64, 0, 16384 + 4096);
  M1_STG(BT, n0 + 128, 0, 16384 + 8192);
  M1_STG(BT, n0 + 192, 0, 16384 + 12288);
  M1_STG(A, m0, 64, 8192);
  M1_STG(A, m0 + 64, 64, 12288);
  asm volatile("s_waitcnt vmcnt(2)" ::: "memory");
  __builtin_amdgcn_s_barrier();

  short8 af[4][2], bfr[2][2];

  for (int T = 0; T < NT; ++T) {
    const int buf = T & 1, nb = buf ^ 1;
    const int abo = buf * 8192;
    const int bbo = 16384 + buf * 16384;
    const int ktn = (T + 1) << 6;
    const int ktn2 = (T + 2) << 6;
    const bool pf1 = (T + 1 < NT), pf2 = (T + 2 < NT);

    // ---- p1: nf 0-1 ----
    M1_LDA;
    M1_LDB(0);
    if (pf1) {
      M1_STG(BT, n0, ktn, 16384 + nb * 16384);
      M1_STG(BT, n0 + 64, ktn, 16384 + nb * 16384 + 4096);
      M1_STG(BT, n0 + 128, ktn, 16384 + nb * 16384 + 8192);
      M1_STG(BT, n0 + 192, ktn, 16384 + nb * 16384 + 12288);
    }
    __builtin_amdgcn_s_barrier();
    asm volatile("s_waitcnt lgkmcnt(0)" ::: "memory");
    __builtin_amdgcn_sched_barrier(0);
    M1_MMA(0);
    __builtin_amdgcn_s_barrier();

    // ---- p2: nf 2-3 ----
    M1_LDB(1);
    if (pf2) {
      M1_STG(A, m0, ktn2, abo);          // A01(T+2) -> current buf (rolling)
      M1_STG(A, m0 + 64, ktn2, abo + 4096);
      asm volatile("s_waitcnt vmcnt(2)" ::: "memory");  // retire tile T+1
    } else if (pf1) {
      asm volatile("s_waitcnt vmcnt(0)" ::: "memory");
    }
    __builtin_amdgcn_s_barrier();
    asm volatile("s_waitcnt lgkmcnt(0)" ::: "memory");
    __builtin_amdgcn_sched_barrier(0);
    M1_MMA(1);
    __builtin_amdgcn_s_barrier();
  }

  // ---- epilogue: bias + f32 store ----
  float bv[4];
#pragma unroll
  for (int nf = 0; nf < 4; ++nf) bv[nf] = bias[n0 + wn * 64 + nf * 16 + l15];
#pragma unroll
  for (int mi = 0; mi < 4; ++mi)
#pragma unroll
    for (int nf = 0; nf < 4; ++nf)
#pragma unroll
      for (int jj = 0; jj < 4; ++jj) {
        const int r = wm * 64 + mi * 16 + g * 4 + jj;
        const int c = wn * 64 + nf * 16 + l15;
        outp[(size_t)(m0 + r) * 2048 + n0 + c] = acc[mi][nf][jj] + bv[nf];
      }
}

// ---------------------------------------------------------------------------
// Causal flash attention. Block = (q-tile 64, bh), 4 waves. K staged in LDS
// (double-buffered, swizzled); V read DIRECTLY from global (L2-resident,
// m169). V loads issued before QK^T; K prefetch issued after them so the
// V-operand wait is counted (leaves K prefetch in flight).
// LDS: Ksl 32KB + Psl 9KB = 41KB -> 3 blocks/CU.
// ---------------------------------------------------------------------------
__global__ __launch_bounds__(256) void attn_kernel(
    const unsigned short* __restrict__ q_ws, const unsigned short* __restrict__ k_ws,
    const unsigned short* __restrict__ vT_ws, unsigned short* __restrict__ attn_ws) {
  __shared__ __align__(16) unsigned short Ksl[2][8192];  // [kv 64][d 128] swizzled
  __shared__ __align__(16) unsigned short Psl[64 * 72];  // [q 64][kv 64+8]

  const int tid = threadIdx.x;
  const int lane = tid & 63;
  const int w = tid >> 6;
  const int l15 = lane & 15, g = lane >> 4;

  const int lid = blockIdx.x;                 // 0..1023
  const int bh  = (lid & 7) + 8 * ((lid >> 3) & 7);   // same bh -> same XCD
  const int qt  = 15 - (lid >> 6);            // big q-tiles dispatch first
  const int q0  = qt * 64;
  const size_t qkb = (size_t)bh * 131072;     // 1024*128
  const unsigned short* kg = k_ws + qkb;
  const unsigned short* vg = vT_ws + qkb;

  short8 qf[4];
#pragma unroll
  for (int ks = 0; ks < 4; ++ks)
    qf[ks] = *(const short8*)&q_ws[qkb + (size_t)(q0 + w * 16 + l15) * 128 + ks * 32 + g * 8];

  f32x4 o[8];
#pragma unroll
  for (int j = 0; j < 8; ++j) o[j] = (f32x4){0.f, 0.f, 0.f, 0.f};
  float lsum[4] = {0.f, 0.f, 0.f, 0.f};

  const float CS = 0.08838834764831845f * 1.4426950408889634f;  // scale*log2e
  const int ntiles = qt + 1;

  // ---- prologue: stage K tile 0 only ----
#pragma unroll
  for (int p = 0; p < 4; ++p) {
    const int base = (w * 4 + p) * 64;        // chunk base (wave-uniform)
    const int L = base + lane, r = L >> 4, s = L & 15;
    const int c = (s & 8) | ((s ^ r) & 7);
    __builtin_amdgcn_global_load_lds(GAS(kg + r * 128 + c * 8),
                                     LAS(&Ksl[0][base * 8]), 16, 0, 0);
  }

  int buf = 0;
  for (int jt = 0; jt < ntiles; ++jt) {
    __syncthreads();   // K tile jt staged; previous buf's readers done

    // ---- V fragments direct from global (issued first -> max cover) ----
    short8 vf0[8], vf1[8];
#pragma unroll
    for (int nd = 0; nd < 8; ++nd)
      vf0[nd] = *(const short8*)&vg[(size_t)(nd * 16 + l15) * 1024 + jt * 64 + g * 8];
#pragma unroll
    for (int nd = 0; nd < 8; ++nd)
      vf1[nd] = *(const short8*)&vg[(size_t)(nd * 16 + l15) * 1024 + jt * 64 + 32 + g * 8];

    if (jt + 1 < ntiles) {  // async K prefetch jt+1 -> other buf (younger than V)
      const unsigned short* kb = kg + (size_t)(jt + 1) * 8192;
      const int nb = buf ^ 1;
#pragma unroll
      for (int p = 0; p < 4; ++p) {
        const int base = (w * 4 + p) * 64;
        const int L = base + lane, r = L >> 4, s = L & 15;
        const int c = (s & 8) | ((s ^ r) & 7);
        __builtin_amdgcn_global_load_lds(GAS(kb + r * 128 + c * 8),
                                         LAS(&Ksl[nb][base * 8]), 16, 0, 0);
      }
    }

    // ---- S = Q K^T from swizzled LDS ----
    f32x4 s[4];
#pragma unroll
    for (int nf = 0; nf < 4; ++nf) s[nf] = (f32x4){0.f, 0.f, 0.f, 0.f};
    __builtin_amdgcn_s_setprio(1);
#pragma unroll
    for (int nf = 0; nf < 4; ++nf) {
      const int r = nf * 16 + l15;
#pragma unroll
      for (int ks = 0; ks < 4; ++ks) {
        const int c = ks * 4 + g;
        const int sl = (c & 8) | ((c ^ r) & 7);
        short8 bfrk = *(const short8*)&Ksl[buf][r * 128 + sl * 8];
        s[nf] = __builtin_amdgcn_mfma_f32_16x16x32_bf16(qf[ks], bfrk, s[nf], 0, 0, 0);
      }
    }
    __builtin_amdgcn_s_setprio(0);

    // ---- softmax numerator (exp2 domain); mask only the diagonal tile ----
    const bool diag = (jt == ntiles - 1);
#pragma unroll
    for (int jj = 0; jj < 4; ++jj) {
      float pv[4];
      if (diag) {
        const int rloc = w * 16 + g * 4 + jj;   // kv0 == q0 on diagonal
#pragma unroll
        for (int nf = 0; nf < 4; ++nf)
          pv[nf] = (nf * 16 + l15 > rloc) ? 0.f
                 : __builtin_amdgcn_exp2f(s[nf][jj] * CS);
      } else {
#pragma unroll
        for (int nf = 0; nf < 4; ++nf)
          pv[nf] = __builtin_amdgcn_exp2f(s[nf][jj] * CS);
      }
      lsum[jj] += (pv[0] + pv[1]) + (pv[2] + pv[3]);
#pragma unroll
      for (int nf = 0; nf < 4; ++nf)
        Psl[(w * 16 + g * 4 + jj) * 72 + nf * 16 + l15] = f2b(pv[nf]);
    }

    // ---- O += P V (P slice wave-private; V from registers) ----
    __builtin_amdgcn_s_setprio(1);
    {
      short8 a0 = *(const short8*)&Psl[(w * 16 + l15) * 72 + g * 8];
#pragma unroll
      for (int nd = 0; nd < 8; ++nd)
        o[nd] = __builtin_amdgcn_mfma_f32_16x16x32_bf16(a0, vf0[nd], o[nd], 0, 0, 0);
    }
    {
      short8 a1 = *(const short8*)&Psl[(w * 16 + l15) * 72 + 32 + g * 8];
#pragma unroll
      for (int nd = 0; nd < 8; ++nd)
        o[nd] = __builtin_amdgcn_mfma_f32_16x16x32_bf16(a1, vf1[nd], o[nd], 0, 0, 0);
    }
    __builtin_amdgcn_s_setprio(0);
    buf ^= 1;
  }

  // ---- epilogue: reduce l across 16 col-lanes, O/l -> attn_ws ----
#pragma unroll
  for (int jj = 0; jj < 4; ++jj) {
    float rs = lsum[jj];
    rs += __shfl_xor(rs, 1);
    rs += __shfl_xor(rs, 2);
    rs += __shfl_xor(rs, 4);
    rs += __shfl_xor(rs, 8);
    const float inv = 1.f / rs;
    const int t = (bh >> 4) * 1024 + q0 + w * 16 + g * 4 + jj;
    unsigned short* dst = attn_ws + (size_t)t * 2048 + (bh & 15) * 128;
#pragma unroll
    for (int nd = 0; nd < 8; ++nd)
      dst[nd * 16 + l15] = f2b(o[nd][jj] * inv);
  }
}

// ---------------------------------------------------------------------------
extern "C" void kernel_launch(void* const* d_in, const int* in_sizes, int n_in,
                              void* d_out, int out_size, void* d_ws, size_t ws_size,
                              hipStream_t stream) {
  const float* hidden = (const float*)d_in[0];
  const float* cosp   = (const float*)d_in[1];
  const float* sinp   = (const float*)d_in[2];
  const float* Wqkv   = (const float*)d_in[3];
  const float* bqkv   = (const float*)d_in[4];
  const float* Wd     = (const float*)d_in[5];
  const float* bd     = (const float*)d_in[6];

  // ws layout (bf16 elems), aliased:
  //   [0, 8.39M)       hidden_bf  -> (dead after G0) attn_bf
  //   [8.39M, 20.97M)  WqkvT      -> (dead after G0) WdT
  //   [20.97M, ...)    q_ws, k_ws, vT_ws (8.39M each)
  unsigned short* ws        = (unsigned short*)d_ws;
  unsigned short* hidden_bf = ws;
  unsigned short* attn_bf   = ws;
  unsigned short* WqkvT     = ws + 8388608;
  unsigned short* WdT       = ws + 8388608;
  unsigned short* q_ws      = ws + 20971520;
  unsigned short* k_ws      = q_ws + 8388608;
  unsigned short* vT_ws     = k_ws + 8388608;

  static bool attr_inited = false;
  if (!attr_inited) {
    hipFuncSetAttribute(reinterpret_cast<const void*>(gemm_qkv_kernel),
                        hipFuncAttributeMaxDynamicSharedMemorySize, 131072);
    hipFuncSetAttribute(reinterpret_cast<const void*>(gemm_out_kernel),
                        hipFuncAttributeMaxDynamicSharedMemorySize, 98304);
    attr_inited = true;
  }

  convert_kernel<<<4096, 256, 0, stream>>>(hidden, hidden_bf);
  transpose_convert_kernel<<<dim3(96, 32), 256, 0, stream>>>(Wqkv, WqkvT, 2048, 6144);
  gemm_qkv_kernel<<<dim3(16, 32), 512, 131072, stream>>>(
      hidden_bf, WqkvT, bqkv, cosp, sinp, q_ws, k_ws, vT_ws);
  attn_kernel<<<1024, 256, 0, stream>>>(q_ws, k_ws, vT_ws, attn_bf);
  transpose_convert_kernel<<<dim3(32, 32), 256, 0, stream>>>(Wd, WdT, 2048, 2048);
  gemm_out_kernel<<<dim3(8, 32), 512, 98304, stream>>>(
      attn_bf, WdT, bd, (float*)d_out);
}

// Round 9
// 337.363 us; speedup vs baseline: 1.1227x; 1.1227x over previous
//
#include <hip/hip_runtime.h>
#include <stdint.h>
#include <math.h>

// ---------------------------------------------------------------------------
// FlashNeoxAttention: qkv = h@Wqkv+b ; rotary(q,k) ; causal flash attn ; @Wd+b
// T=4096 (B=4 x S=1024), H=16 heads x D=128, ROT=16 (first 32 dims rotated)
// R12: (a) attn reverted to R5 V-staged form (R11's direct V-fragment reads
//      were 4x-uncoalesced at 64B granularity -> +43us regression).
//      (b) launch fusion 6 -> 4: pre_kernel = convert(4096 blks) + WqkvT
//      transpose (3072 blks) routed by blockIdx; Wd transpose folded into the
//      attn launch as blocks 1024..2047 (reuses Ksl LDS; backfills attn tail).
//      Aliasing audit: WdT overwrites WqkvT region only after gemm_qkv done
//      (stream order); attn_bf overwrites hidden_bf after gemm_qkv done.
//      gemm_qkv / gemm_out: unchanged R8/R5-proven forms.
// ---------------------------------------------------------------------------

typedef __attribute__((ext_vector_type(8))) short short8;   // 8 x bf16 (4 VGPR)
typedef __attribute__((ext_vector_type(4))) float f32x4;    // MFMA C/D frag

__device__ __forceinline__ unsigned short f2b(float f) {
  union { float f; unsigned int i; } x; x.f = f;
  unsigned int r = x.i + 0x7FFFu + ((x.i >> 16) & 1u);  // round-nearest-even
  return (unsigned short)(r >> 16);
}

#define GAS(p) ((const __attribute__((address_space(1))) void*)(p))
#define LAS(p) ((__attribute__((address_space(3))) void*)(p))

// ---------------------------------------------------------------------------
// pre_kernel: blocks [0,4096) = f32->bf16 convert of hidden (8 elems/thread);
//             blocks [4096,7168) = Wqkv transpose+convert f32[K=2048][N=6144]
//             -> bf16 [N][K], 64x64 tiles. Bodies identical to proven forms.
// ---------------------------------------------------------------------------
__global__ __launch_bounds__(256) void pre_kernel(
    const float* __restrict__ hidden, unsigned short* __restrict__ hidden_bf,
    const float* __restrict__ Wqkv, unsigned short* __restrict__ WqkvT) {
  __shared__ __align__(16) unsigned short tile[64][72];  // +8 pad (t1 path)
  const int tid = threadIdx.x;

  if (blockIdx.x < 4096) {  // ---- convert path ----
    const size_t base = ((size_t)blockIdx.x * 256 + tid) * 8;
    float4 v0 = *(const float4*)&hidden[base];
    float4 v1 = *(const float4*)&hidden[base + 4];
    unsigned short t8[8] = {f2b(v0.x), f2b(v0.y), f2b(v0.z), f2b(v0.w),
                            f2b(v1.x), f2b(v1.y), f2b(v1.z), f2b(v1.w)};
    *(uint4*)&hidden_bf[base] = *(uint4*)t8;
    return;
  }

  // ---- Wqkv transpose path ----
  const int bid = blockIdx.x - 4096;          // 0..3071
  const int n0 = (bid % 96) * 64, k0 = (bid / 96) * 64;
  const int K = 2048, N = 6144;
#pragma unroll
  for (int p = 0; p < 2; ++p) {
    const int idx = p * 256 + tid;
    const int r = idx >> 3, c8 = idx & 7;
    const float* sp = &Wqkv[(size_t)(k0 + r) * N + n0 + c8 * 8];
    float4 v0 = *(const float4*)sp;
    float4 v1 = *(const float4*)(sp + 4);
    unsigned short t8[8] = {f2b(v0.x), f2b(v0.y), f2b(v0.z), f2b(v0.w),
                            f2b(v1.x), f2b(v1.y), f2b(v1.z), f2b(v1.w)};
    *(uint4*)&tile[r][c8 * 8] = *(uint4*)t8;
  }
  __syncthreads();
#pragma unroll
  for (int p = 0; p < 2; ++p) {
    const int idx = p * 256 + tid;
    const int r = idx >> 3, c8 = idx & 7;
    unsigned short out[8];
#pragma unroll
    for (int j = 0; j < 8; ++j) out[j] = tile[c8 * 8 + j][r];
    *(uint4*)&WqkvT[(size_t)(n0 + r) * K + k0 + c8 * 8] = *(uint4*)out;
  }
}

// ---------------------------------------------------------------------------
// gemm_qkv (R8-proven): 128(M) x 384(N) tile, BK=64, 8 waves (2Mx4N, wave
// 64x96), 3 phases/K-tile, grid 32x16 = 512 blocks = 2 exact rounds.
// Units: A(128x64), B0,B1,B2(128x64). LDS elems:
//   A: buf*8192 (0..16384); B: 16384 + buf*24576 + u*8192. Total 128 KiB.
// RACE-SAFE calendar: p1 stages A,B0,B1(T+1); p2 stages B2(T+1);
// p3: vmcnt(0) DRAIN + barrier => tile T+1 resident 1 phase + 1 barrier
// before any read of it.
// ---------------------------------------------------------------------------

#define QSTAGE(SRC, R0, KT, LDSOFF)                                           \
  do {                                                                        \
    _Pragma("unroll") for (int p_ = 0; p_ < 2; ++p_) {                        \
      const int cb_ = w * 2 + p_;                                             \
      __builtin_amdgcn_global_load_lds(                                       \
          GAS((SRC) + (size_t)((R0) + cb_ * 8 + rl) * 2048 + (KT) + cg * 8),  \
          LAS(smem + (LDSOFF) + cb_ * 512), 16, 0, 0);                        \
    }                                                                         \
  } while (0)

#define QLDA                                                                  \
  do {                                                                        \
    _Pragma("unroll") for (int mf_ = 0; mf_ < 4; ++mf_) {                     \
      const int r_ = wm * 64 + mf_ * 16 + l15;                                \
      const unsigned short* rp_ = smem + abo + r_ * 64;                       \
      _Pragma("unroll") for (int ks_ = 0; ks_ < 2; ++ks_)                     \
        af[mf_][ks_] = *(const short8*)&rp_[((ks_ * 4 + g) ^ (r_ & 7)) * 8];  \
    }                                                                         \
  } while (0)

#define QLDB(NH)                                                              \
  do {                                                                        \
    _Pragma("unroll") for (int nf_ = 0; nf_ < 2; ++nf_) {                     \
      const int r_ = wn * 96 + (NH) * 32 + nf_ * 16 + l15;                    \
      const unsigned short* rp_ = smem + 16384 + bbo + r_ * 64;               \
      _Pragma("unroll") for (int ks_ = 0; ks_ < 2; ++ks_)                     \
        bfr[nf_][ks_] = *(const short8*)&rp_[((ks_ * 4 + g) ^ (r_ & 7)) * 8]; \
    }                                                                         \
  } while (0)

#define QMMA(NH)                                                              \
  do {                                                                        \
    __builtin_amdgcn_s_setprio(1);                                            \
    _Pragma("unroll") for (int mf_ = 0; mf_ < 4; ++mf_)                       \
    _Pragma("unroll") for (int nf_ = 0; nf_ < 2; ++nf_)                       \
    _Pragma("unroll") for (int ks_ = 0; ks_ < 2; ++ks_)                       \
      acc[mf_][(NH) * 2 + nf_] = __builtin_amdgcn_mfma_f32_16x16x32_bf16(     \
          af[mf_][ks_], bfr[nf_][ks_], acc[mf_][(NH) * 2 + nf_], 0, 0, 0);    \
    __builtin_amdgcn_s_setprio(0);                                            \
    __builtin_amdgcn_sched_barrier(0);                                        \
  } while (0)

__global__ __launch_bounds__(512, 2) void gemm_qkv_kernel(
    const unsigned short* __restrict__ A, const unsigned short* __restrict__ BT,
    const float* __restrict__ bias,
    const float* __restrict__ cosp, const float* __restrict__ sinp,
    unsigned short* __restrict__ q_ws, unsigned short* __restrict__ k_ws,
    unsigned short* __restrict__ vT_ws) {
  extern __shared__ unsigned short smem[];  // 65536 elems = 128 KiB
  const int NT = 32;

  const int tid = threadIdx.x;
  const int lane = tid & 63;
  const int w = tid >> 6;            // wave 0..7
  const int wm = w >> 2, wn = w & 3; // 2M x 4N; wave tile 64 x 96
  const int l15 = lane & 15, g = lane >> 4;
  const int rl = lane >> 3;                // staging: row within 8-row chunk
  const int cg = (lane & 7) ^ rl;          // pre-swizzled global 16B-chunk

  // bijective XCD swizzle (512 % 8 == 0)
  const int nbx = gridDim.x;               // 16 (n tiles)
  const int cpx = (nbx * gridDim.y) >> 3;
  const int orig = blockIdx.y * nbx + blockIdx.x;
  const int wgid = (orig & 7) * cpx + (orig >> 3);
  const int bx = wgid % nbx, by = wgid / nbx;
  const int m0 = by * 128, n0 = bx * 384;

  f32x4 acc[4][6];
#pragma unroll
  for (int i = 0; i < 4; ++i)
#pragma unroll
    for (int j = 0; j < 6; ++j) acc[i][j] = (f32x4){0.f, 0.f, 0.f, 0.f};

  // prologue: stage tile 0 (A, B0, B1, B2) into buf 0, then DRAIN.
  QSTAGE(A, m0, 0, 0);
  QSTAGE(BT, n0, 0, 16384);
  QSTAGE(BT, n0 + 128, 0, 24576);
  QSTAGE(BT, n0 + 256, 0, 32768);
  asm volatile("s_waitcnt vmcnt(0)" ::: "memory");  // tile0 resident
  __builtin_amdgcn_s_barrier();

  short8 af[4][2], bfr[2][2];

  for (int T = 0; T < NT; ++T) {
    const int buf = T & 1, nb = buf ^ 1;
    const int abo = buf * 8192;
    const int bbo = buf * 24576;
    const int nabo = nb * 8192;
    const int nbbo = nb * 24576;
    const int ktn = (T + 1) << 6;
    const bool pf1 = (T + 1 < NT);

    // ---- p1: stage A,B0,B1(T+1); read A,B_nf01(T) ----
    if (pf1) {
      QSTAGE(A, m0, ktn, nabo);
      QSTAGE(BT, n0, ktn, 16384 + nbbo);
      QSTAGE(BT, n0 + 128, ktn, 24576 + nbbo);
    }
    QLDA;
    QLDB(0);
    __builtin_amdgcn_s_barrier();
    asm volatile("s_waitcnt lgkmcnt(0)" ::: "memory");
    __builtin_amdgcn_sched_barrier(0);
    QMMA(0);
    __builtin_amdgcn_s_barrier();

    // ---- p2: stage B2(T+1); read B_nf23(T) ----
    if (pf1) QSTAGE(BT, n0 + 256, ktn, 32768 + nbbo);
    QLDB(1);
    __builtin_amdgcn_s_barrier();
    asm volatile("s_waitcnt lgkmcnt(0)" ::: "memory");
    __builtin_amdgcn_sched_barrier(0);
    QMMA(1);
    __builtin_amdgcn_s_barrier();

    // ---- p3: DRAIN (tile T+1 fully resident); read B_nf45(T) ----
    QLDB(2);
    asm volatile("s_waitcnt vmcnt(0)" ::: "memory");  // retire tile T+1 (all)
    __builtin_amdgcn_s_barrier();
    asm volatile("s_waitcnt lgkmcnt(0)" ::: "memory");
    __builtin_amdgcn_sched_barrier(0);
    QMMA(2);
    __builtin_amdgcn_s_barrier();
  }

  // ---- epilogue: bias (cols gc = n0 + wn*96 + nf*16 + l15) ----
  float bv[6];
#pragma unroll
  for (int nf = 0; nf < 6; ++nf) bv[nf] = bias[n0 + wn * 96 + nf * 16 + l15];
#pragma unroll
  for (int mi = 0; mi < 4; ++mi)
#pragma unroll
    for (int nf = 0; nf < 6; ++nf)
#pragma unroll
      for (int jj = 0; jj < 4; ++jj) acc[mi][nf][jj] += bv[nf];

  // ---- rotary: group nf has head-local idx hg=((6*wn+nf)&7); rotate pair
  //      (nf,nf+1) where hg==0, only for q/k col-blocks. Never splits a wave.
#pragma unroll
  for (int nf = 0; nf < 5; ++nf) {
    if (((6 * wn + nf) & 7) == 0) {
      const int jb = (wn * 96 + nf * 16) >> 7;          // col-block 0..2
      const int whichj = (n0 + jb * 128) >> 11;          // 0=q 1=k 2=v
      if (whichj < 2) {
#pragma unroll
        for (int mi = 0; mi < 4; ++mi)
#pragma unroll
          for (int jj = 0; jj < 4; ++jj) {
            const int t = m0 + wm * 64 + mi * 16 + g * 4 + jj;
            const float c = cosp[t * 16 + l15];
            const float s = sinp[t * 16 + l15];
            const float a1 = acc[mi][nf][jj], a2 = acc[mi][nf + 1][jj];
            acc[mi][nf][jj] = a1 * c - a2 * s;
            acc[mi][nf + 1][jj] = a1 * s + a2 * c;
          }
      }
    }
  }

  // ---- write C into 3 per-head LDS sub-tiles [128][136] (v transposed) ----
  const int b = m0 >> 10, s0v = m0 & 1023;
#pragma unroll
  for (int mi = 0; mi < 4; ++mi)
#pragma unroll
    for (int nf = 0; nf < 6; ++nf)
#pragma unroll
      for (int jj = 0; jj < 4; ++jj) {
        const int r = wm * 64 + mi * 16 + g * 4 + jj;    // token-local 0..127
        const int gc = wn * 96 + nf * 16 + l15;          // tile col 0..383
        const int jb = gc >> 7, lc = gc & 127;
        const int whichj = (n0 + jb * 128) >> 11;
        const unsigned short hv = f2b(acc[mi][nf][jj]);
        if (whichj < 2) smem[jb * 17408 + r * 136 + lc] = hv;
        else            smem[jb * 17408 + lc * 136 + r] = hv;
      }
  __syncthreads();

  // ---- flush sub-tiles, per-block q/k/v routing ----
#pragma unroll
  for (int jb = 0; jb < 3; ++jb) {
    const int gcb = n0 + jb * 128;
    const int whichj = gcb >> 11;
    const int head = (gcb >> 7) & 15;
#pragma unroll
    for (int p4 = 0; p4 < 4; ++p4) {
      const int idx = p4 * 512 + tid;
      const int rr = idx >> 4, c8 = idx & 15;
      uint4 v = *(const uint4*)&smem[jb * 17408 + rr * 136 + c8 * 8];
      unsigned short* dp;
      if (whichj == 0)
        dp = q_ws + ((size_t)(b * 16 + head) * 1024 + s0v + rr) * 128 + c8 * 8;
      else if (whichj == 1)
        dp = k_ws + ((size_t)(b * 16 + head) * 1024 + s0v + rr) * 128 + c8 * 8;
      else  // v: sub-tile row rr = head-dim d, cols = local tokens
        dp = vT_ws + ((size_t)(b * 16 + head) * 128 + rr) * 1024 + s0v + c8 * 8;
      *(uint4*)dp = v;
    }
  }
}

// ---------------------------------------------------------------------------
// gemm_out: C[4096][2048] f32 = A @ WdT^T + bias. Tile 128(M) x 256(N), BK=64,
// grid 8x32 = 256 blocks (exactly one full dispatch round). 8 waves (2Mx4N),
// wave out 64x64, 2 phases/K-tile (nf01 / nf23), 16 MFMA each. (R5 form.)
// ---------------------------------------------------------------------------

#define M1_STG(SRC, R0, KT, LB)                                               \
  __builtin_amdgcn_global_load_lds(                                           \
      GAS((SRC) + (size_t)((R0) + w * 8 + rl) * 2048 + (KT) + cg * 8),        \
      LAS(smem + (LB) + w * 512), 16, 0, 0)

#define M1_LDA                                                                \
  do {                                                                        \
    _Pragma("unroll") for (int mf_ = 0; mf_ < 4; ++mf_) {                     \
      const int r_ = wm * 64 + mf_ * 16 + l15;                                \
      const unsigned short* rp_ = smem + abo + r_ * 64;                       \
      _Pragma("unroll") for (int ks_ = 0; ks_ < 2; ++ks_)                     \
        af[mf_][ks_] = *(const short8*)&rp_[((ks_ * 4 + g) ^ (r_ & 7)) * 8];  \
    }                                                                         \
  } while (0)

#define M1_LDB(NH)                                                            \
  do {                                                                        \
    _Pragma("unroll") for (int nf_ = 0; nf_ < 2; ++nf_) {                     \
      const int r_ = wn * 64 + (NH) * 32 + nf_ * 16 + l15;                    \
      const unsigned short* rp_ = smem + bbo + r_ * 64;                       \
      _Pragma("unroll") for (int ks_ = 0; ks_ < 2; ++ks_)                     \
        bfr[nf_][ks_] = *(const short8*)&rp_[((ks_ * 4 + g) ^ (r_ & 7)) * 8]; \
    }                                                                         \
  } while (0)

#define M1_MMA(NH)                                                            \
  do {                                                                        \
    __builtin_amdgcn_s_setprio(1);                                            \
    _Pragma("unroll") for (int mf_ = 0; mf_ < 4; ++mf_)                       \
    _Pragma("unroll") for (int nf_ = 0; nf_ < 2; ++nf_)                       \
    _Pragma("unroll") for (int ks_ = 0; ks_ < 2; ++ks_)                       \
      acc[mf_][(NH) * 2 + nf_] = __builtin_amdgcn_mfma_f32_16x16x32_bf16(     \
          af[mf_][ks_], bfr[nf_][ks_], acc[mf_][(NH) * 2 + nf_], 0, 0, 0);    \
    __builtin_amdgcn_s_setprio(0);                                            \
    __builtin_amdgcn_sched_barrier(0);                                        \
  } while (0)

__global__ __launch_bounds__(512, 2) void gemm_out_kernel(
    const unsigned short* __restrict__ A, const unsigned short* __restrict__ BT,
    const float* __restrict__ bias, float* __restrict__ outp) {
  extern __shared__ unsigned short smem[];  // 49152 elems = 96 KiB
  const int NT = 32;

  const int tid = threadIdx.x;
  const int lane = tid & 63;
  const int w = tid >> 6;
  const int wm = w >> 2, wn = w & 3;   // 2M x 4N, wave out 64x64
  const int l15 = lane & 15, g = lane >> 4;
  const int rl = lane >> 3;
  const int cg = (lane & 7) ^ rl;

  // bijective XCD swizzle (256 % 8 == 0)
  const int nbx = gridDim.x;
  const int cpx = (nbx * gridDim.y) >> 3;
  const int orig = blockIdx.y * nbx + blockIdx.x;
  const int wgid = (orig & 7) * cpx + (orig >> 3);
  const int bx = wgid % nbx, by = wgid / nbx;
  const int m0 = by * 128, n0 = bx * 256;

  f32x4 acc[4][4];
#pragma unroll
  for (int i = 0; i < 4; ++i)
#pragma unroll
    for (int j = 0; j < 4; ++j) acc[i][j] = (f32x4){0.f, 0.f, 0.f, 0.f};

  // prologue: A01(0), BQ0..3(0), A01(1); gate retires tile0 (6 loads)
  M1_STG(A, m0, 0, 0);
  M1_STG(A, m0 + 64, 0, 4096);
  M1_STG(BT, n0, 0, 16384);
  M1_STG(BT, n0 + 64, 0, 16384 + 4096);
  M1_STG(BT, n0 + 128, 0, 16384 + 8192);
  M1_STG(BT, n0 + 192, 0, 16384 + 12288);
  M1_STG(A, m0, 64, 8192);
  M1_STG(A, m0 + 64, 64, 12288);
  asm volatile("s_waitcnt vmcnt(2)" ::: "memory");
  __builtin_amdgcn_s_barrier();

  short8 af[4][2], bfr[2][2];

  for (int T = 0; T < NT; ++T) {
    const int buf = T & 1, nb = buf ^ 1;
    const int abo = buf * 8192;
    const int bbo = 16384 + buf * 16384;
    const int ktn = (T + 1) << 6;
    const int ktn2 = (T + 2) << 6;
    const bool pf1 = (T + 1 < NT), pf2 = (T + 2 < NT);

    // ---- p1: nf 0-1 ----
    M1_LDA;
    M1_LDB(0);
    if (pf1) {
      M1_STG(BT, n0, ktn, 16384 + nb * 16384);
      M1_STG(BT, n0 + 64, ktn, 16384 + nb * 16384 + 4096);
      M1_STG(BT, n0 + 128, ktn, 16384 + nb * 16384 + 8192);
      M1_STG(BT, n0 + 192, ktn, 16384 + nb * 16384 + 12288);
    }
    __builtin_amdgcn_s_barrier();
    asm volatile("s_waitcnt lgkmcnt(0)" ::: "memory");
    __builtin_amdgcn_sched_barrier(0);
    M1_MMA(0);
    __builtin_amdgcn_s_barrier();

    // ---- p2: nf 2-3 ----
    M1_LDB(1);
    if (pf2) {
      M1_STG(A, m0, ktn2, abo);          // A01(T+2) -> current buf (rolling)
      M1_STG(A, m0 + 64, ktn2, abo + 4096);
      asm volatile("s_waitcnt vmcnt(2)" ::: "memory");  // retire tile T+1
    } else if (pf1) {
      asm volatile("s_waitcnt vmcnt(0)" ::: "memory");
    }
    __builtin_amdgcn_s_barrier();
    asm volatile("s_waitcnt lgkmcnt(0)" ::: "memory");
    __builtin_amdgcn_sched_barrier(0);
    M1_MMA(1);
    __builtin_amdgcn_s_barrier();
  }

  // ---- epilogue: bias + f32 store ----
  float bv[4];
#pragma unroll
  for (int nf = 0; nf < 4; ++nf) bv[nf] = bias[n0 + wn * 64 + nf * 16 + l15];
#pragma unroll
  for (int mi = 0; mi < 4; ++mi)
#pragma unroll
    for (int nf = 0; nf < 4; ++nf)
#pragma unroll
      for (int jj = 0; jj < 4; ++jj) {
        const int r = wm * 64 + mi * 16 + g * 4 + jj;
        const int c = wn * 64 + nf * 16 + l15;
        outp[(size_t)(m0 + r) * 2048 + n0 + c] = acc[mi][nf][jj] + bv[nf];
      }
}

// ---------------------------------------------------------------------------
// attn + Wd-transpose fused. Blocks [0,1024): causal flash attention (R5
// form: K,V staged in LDS via global_load_lds, XOR-swizzled, double-buffered,
// 1 barrier/tile, T5 setprio). Blocks [1024,2048): Wd f32[2048][2048] ->
// WdT bf16 (64x64 tiles; reuses Ksl storage; independent of attn; WdT region
// is free once gemm_qkv completed, which precedes this launch).
// ---------------------------------------------------------------------------
__global__ __launch_bounds__(256) void attn_kernel(
    const unsigned short* __restrict__ q_ws, const unsigned short* __restrict__ k_ws,
    const unsigned short* __restrict__ vT_ws, unsigned short* __restrict__ attn_ws,
    const float* __restrict__ Wd, unsigned short* __restrict__ WdT) {
  __shared__ __align__(16) unsigned short Ksl[2][8192];  // [kv 64][d 128] swizzled
  __shared__ __align__(16) unsigned short Vsl[2][8192];  // [d 128][kv 64] swizzled
  __shared__ __align__(16) unsigned short Psl[64 * 72];  // [q 64][kv 64+8]

  const int tid = threadIdx.x;

  if (blockIdx.x >= 1024) {  // ---- Wd transpose path (reuses Ksl as tile) ----
    unsigned short (*tile)[72] = reinterpret_cast<unsigned short(*)[72]>(&Ksl[0][0]);
    const int bid = blockIdx.x - 1024;        // 0..1023
    const int n0 = (bid & 31) * 64, k0 = (bid >> 5) * 64;
    const int K = 2048, N = 2048;
#pragma unroll
    for (int p = 0; p < 2; ++p) {
      const int idx = p * 256 + tid;
      const int r = idx >> 3, c8 = idx & 7;
      const float* sp = &Wd[(size_t)(k0 + r) * N + n0 + c8 * 8];
      float4 v0 = *(const float4*)sp;
      float4 v1 = *(const float4*)(sp + 4);
      unsigned short t8[8] = {f2b(v0.x), f2b(v0.y), f2b(v0.z), f2b(v0.w),
                              f2b(v1.x), f2b(v1.y), f2b(v1.z), f2b(v1.w)};
      *(uint4*)&tile[r][c8 * 8] = *(uint4*)t8;
    }
    __syncthreads();
#pragma unroll
    for (int p = 0; p < 2; ++p) {
      const int idx = p * 256 + tid;
      const int r = idx >> 3, c8 = idx & 7;
      unsigned short out[8];
#pragma unroll
      for (int j = 0; j < 8; ++j) out[j] = tile[c8 * 8 + j][r];
      *(uint4*)&WdT[(size_t)(n0 + r) * K + k0 + c8 * 8] = *(uint4*)out;
    }
    return;
  }

  // ---- attention path (R5-proven) ----
  const int lane = tid & 63;
  const int w = tid >> 6;
  const int l15 = lane & 15, g = lane >> 4;

  const int lid = blockIdx.x;                 // 0..1023
  const int bh  = (lid & 7) + 8 * ((lid >> 3) & 7);   // same bh -> same XCD
  const int qt  = 15 - (lid >> 6);            // big q-tiles dispatch first
  const int q0  = qt * 64;
  const size_t qkb = (size_t)bh * 131072;     // 1024*128
  const unsigned short* kg = k_ws + qkb;
  const unsigned short* vg = vT_ws + qkb;

  short8 qf[4];
#pragma unroll
  for (int ks = 0; ks < 4; ++ks)
    qf[ks] = *(const short8*)&q_ws[qkb + (size_t)(q0 + w * 16 + l15) * 128 + ks * 32 + g * 8];

  f32x4 o[8];
#pragma unroll
  for (int j = 0; j < 8; ++j) o[j] = (f32x4){0.f, 0.f, 0.f, 0.f};
  float lsum[4] = {0.f, 0.f, 0.f, 0.f};

  const float CS = 0.08838834764831845f * 1.4426950408889634f;  // scale*log2e
  const int ntiles = qt + 1;

#pragma unroll
  for (int p = 0; p < 4; ++p) {
    const int base = (w * 4 + p) * 64;        // chunk base (wave-uniform)
    {
      const int L = base + lane, r = L >> 4, s = L & 15;
      const int c = (s & 8) | ((s ^ r) & 7);
      __builtin_amdgcn_global_load_lds(GAS(kg + r * 128 + c * 8),
                                       LAS(&Ksl[0][base * 8]), 16, 0, 0);
    }
    {
      const int L = base + lane, r = L >> 3, s = L & 7;
      const int c = (s ^ r) & 7;
      __builtin_amdgcn_global_load_lds(GAS(vg + (size_t)r * 1024 + c * 8),
                                       LAS(&Vsl[0][base * 8]), 16, 0, 0);
    }
  }

  int buf = 0;
  for (int jt = 0; jt < ntiles; ++jt) {
    __syncthreads();   // tile jt staged; previous buf's readers done

    if (jt + 1 < ntiles) {  // async prefetch jt+1 -> other buf
      const unsigned short* kb = kg + (size_t)(jt + 1) * 8192;
      const unsigned short* vb = vg + (jt + 1) * 64;
      const int nb = buf ^ 1;
#pragma unroll
      for (int p = 0; p < 4; ++p) {
        const int base = (w * 4 + p) * 64;
        {
          const int L = base + lane, r = L >> 4, s = L & 15;
          const int c = (s & 8) | ((s ^ r) & 7);
          __builtin_amdgcn_global_load_lds(GAS(kb + r * 128 + c * 8),
                                           LAS(&Ksl[nb][base * 8]), 16, 0, 0);
        }
        {
          const int L = base + lane, r = L >> 3, s = L & 7;
          const int c = (s ^ r) & 7;
          __builtin_amdgcn_global_load_lds(GAS(vb + (size_t)r * 1024 + c * 8),
                                           LAS(&Vsl[nb][base * 8]), 16, 0, 0);
        }
      }
    }

    f32x4 s[4];
#pragma unroll
    for (int nf = 0; nf < 4; ++nf) s[nf] = (f32x4){0.f, 0.f, 0.f, 0.f};
    __builtin_amdgcn_s_setprio(1);
#pragma unroll
    for (int nf = 0; nf < 4; ++nf) {
      const int r = nf * 16 + l15;
#pragma unroll
      for (int ks = 0; ks < 4; ++ks) {
        const int c = ks * 4 + g;
        const int sl = (c & 8) | ((c ^ r) & 7);
        short8 bfrk = *(const short8*)&Ksl[buf][r * 128 + sl * 8];
        s[nf] = __builtin_amdgcn_mfma_f32_16x16x32_bf16(qf[ks], bfrk, s[nf], 0, 0, 0);
      }
    }
    __builtin_amdgcn_s_setprio(0);

    const bool diag = (jt == ntiles - 1);
#pragma unroll
    for (int jj = 0; jj < 4; ++jj) {
      float pv[4];
      if (diag) {
        const int rloc = w * 16 + g * 4 + jj;   // kv0 == q0 on diagonal
#pragma unroll
        for (int nf = 0; nf < 4; ++nf)
          pv[nf] = (nf * 16 + l15 > rloc) ? 0.f
                 : __builtin_amdgcn_exp2f(s[nf][jj] * CS);
      } else {
#pragma unroll
        for (int nf = 0; nf < 4; ++nf)
          pv[nf] = __builtin_amdgcn_exp2f(s[nf][jj] * CS);
      }
      lsum[jj] += (pv[0] + pv[1]) + (pv[2] + pv[3]);
#pragma unroll
      for (int nf = 0; nf < 4; ++nf)
        Psl[(w * 16 + g * 4 + jj) * 72 + nf * 16 + l15] = f2b(pv[nf]);
    }

    __builtin_amdgcn_s_setprio(1);
#pragma unroll
    for (int ks = 0; ks < 2; ++ks) {
      short8 a0 = *(const short8*)&Psl[(w * 16 + l15) * 72 + ks * 32 + g * 8];
#pragma unroll
      for (int nd = 0; nd < 8; ++nd) {
        const int r = nd * 16 + l15;
        const int c = ks * 4 + g;
        const int sl = (c ^ r) & 7;
        short8 bfrv = *(const short8*)&Vsl[buf][r * 64 + sl * 8];
        o[nd] = __builtin_amdgcn_mfma_f32_16x16x32_bf16(a0, bfrv, o[nd], 0, 0, 0);
      }
    }
    __builtin_amdgcn_s_setprio(0);
    buf ^= 1;
  }

#pragma unroll
  for (int jj = 0; jj < 4; ++jj) {
    float rs = lsum[jj];
    rs += __shfl_xor(rs, 1);
    rs += __shfl_xor(rs, 2);
    rs += __shfl_xor(rs, 4);
    rs += __shfl_xor(rs, 8);
    const float inv = 1.f / rs;
    const int t = (bh >> 4) * 1024 + q0 + w * 16 + g * 4 + jj;
    unsigned short* dst = attn_ws + (size_t)t * 2048 + (bh & 15) * 128;
#pragma unroll
    for (int nd = 0; nd < 8; ++nd)
      dst[nd * 16 + l15] = f2b(o[nd][jj] * inv);
  }
}

// ---------------------------------------------------------------------------
extern "C" void kernel_launch(void* const* d_in, const int* in_sizes, int n_in,
                              void* d_out, int out_size, void* d_ws, size_t ws_size,
                              hipStream_t stream) {
  const float* hidden = (const float*)d_in[0];
  const float* cosp   = (const float*)d_in[1];
  const float* sinp   = (const float*)d_in[2];
  const float* Wqkv   = (const float*)d_in[3];
  const float* bqkv   = (const float*)d_in[4];
  const float* Wd     = (const float*)d_in[5];
  const float* bd     = (const float*)d_in[6];

  // ws layout (bf16 elems), aliased:
  //   [0, 8.39M)       hidden_bf  -> (dead after gemm_qkv) attn_bf
  //   [8.39M, 20.97M)  WqkvT      -> (dead after gemm_qkv) WdT
  //   [20.97M, ...)    q_ws, k_ws, vT_ws (8.39M each)
  unsigned short* ws        = (unsigned short*)d_ws;
  unsigned short* hidden_bf = ws;
  unsigned short* attn_bf   = ws;
  unsigned short* WqkvT     = ws + 8388608;
  unsigned short* WdT       = ws + 8388608;
  unsigned short* q_ws      = ws + 20971520;
  unsigned short* k_ws      = q_ws + 8388608;
  unsigned short* vT_ws     = k_ws + 8388608;

  static bool attr_inited = false;
  if (!attr_inited) {
    hipFuncSetAttribute(reinterpret_cast<const void*>(gemm_qkv_kernel),
                        hipFuncAttributeMaxDynamicSharedMemorySize, 131072);
    hipFuncSetAttribute(reinterpret_cast<const void*>(gemm_out_kernel),
                        hipFuncAttributeMaxDynamicSharedMemorySize, 98304);
    attr_inited = true;
  }

  pre_kernel<<<7168, 256, 0, stream>>>(hidden, hidden_bf, Wqkv, WqkvT);
  gemm_qkv_kernel<<<dim3(16, 32), 512, 131072, stream>>>(
      hidden_bf, WqkvT, bqkv, cosp, sinp, q_ws, k_ws, vT_ws);
  attn_kernel<<<2048, 256, 0, stream>>>(q_ws, k_ws, vT_ws, attn_bf, Wd, WdT);
  gemm_out_kernel<<<dim3(8, 32), 512, 98304, stream>>>(
      attn_bf, WdT, bd, (float*)d_out);
}

// Round 10
// 316.907 us; speedup vs baseline: 1.1952x; 1.0645x over previous
//
#include <hip/hip_runtime.h>
#include <stdint.h>
#include <math.h>

// ---------------------------------------------------------------------------
// FlashNeoxAttention: qkv = h@Wqkv+b ; rotary(q,k) ; causal flash attn ; @Wd+b
// T=4096 (B=4 x S=1024), H=16 heads x D=128, ROT=16 (first 32 dims rotated)
// R13: minimal-sync GEMMs. With a FULL double buffer (stage->nb, read->cur)
//      the only required sync is ONE __syncthreads() per K-tile (drains vmcnt
//      -> T+1 resident; joins all readers of cur before T+1's stages reuse
//      it). Removes 5 of 6 barriers + manual fences per tile from gemm_qkv
//      (and the counted-gate/rolling-A machinery from gemm_out); compiler
//      schedules the whole tile (m97-style, its strong regime). VGPR budget
//      at 2 waves/SIMD is 256, so all frags can stay live.
//      attn / pre_kernel unchanged (R9-proven). Staging addresses unchanged.
// ---------------------------------------------------------------------------

typedef __attribute__((ext_vector_type(8))) short short8;   // 8 x bf16 (4 VGPR)
typedef __attribute__((ext_vector_type(4))) float f32x4;    // MFMA C/D frag

__device__ __forceinline__ unsigned short f2b(float f) {
  union { float f; unsigned int i; } x; x.f = f;
  unsigned int r = x.i + 0x7FFFu + ((x.i >> 16) & 1u);  // round-nearest-even
  return (unsigned short)(r >> 16);
}

#define GAS(p) ((const __attribute__((address_space(1))) void*)(p))
#define LAS(p) ((__attribute__((address_space(3))) void*)(p))

// ---------------------------------------------------------------------------
// pre_kernel: blocks [0,4096) = f32->bf16 convert of hidden (8 elems/thread);
//             blocks [4096,7168) = Wqkv transpose+convert f32[K=2048][N=6144]
//             -> bf16 [N][K], 64x64 tiles.
// ---------------------------------------------------------------------------
__global__ __launch_bounds__(256) void pre_kernel(
    const float* __restrict__ hidden, unsigned short* __restrict__ hidden_bf,
    const float* __restrict__ Wqkv, unsigned short* __restrict__ WqkvT) {
  __shared__ __align__(16) unsigned short tile[64][72];  // +8 pad (t1 path)
  const int tid = threadIdx.x;

  if (blockIdx.x < 4096) {  // ---- convert path ----
    const size_t base = ((size_t)blockIdx.x * 256 + tid) * 8;
    float4 v0 = *(const float4*)&hidden[base];
    float4 v1 = *(const float4*)&hidden[base + 4];
    unsigned short t8[8] = {f2b(v0.x), f2b(v0.y), f2b(v0.z), f2b(v0.w),
                            f2b(v1.x), f2b(v1.y), f2b(v1.z), f2b(v1.w)};
    *(uint4*)&hidden_bf[base] = *(uint4*)t8;
    return;
  }

  // ---- Wqkv transpose path ----
  const int bid = blockIdx.x - 4096;          // 0..3071
  const int n0 = (bid % 96) * 64, k0 = (bid / 96) * 64;
  const int K = 2048, N = 6144;
#pragma unroll
  for (int p = 0; p < 2; ++p) {
    const int idx = p * 256 + tid;
    const int r = idx >> 3, c8 = idx & 7;
    const float* sp = &Wqkv[(size_t)(k0 + r) * N + n0 + c8 * 8];
    float4 v0 = *(const float4*)sp;
    float4 v1 = *(const float4*)(sp + 4);
    unsigned short t8[8] = {f2b(v0.x), f2b(v0.y), f2b(v0.z), f2b(v0.w),
                            f2b(v1.x), f2b(v1.y), f2b(v1.z), f2b(v1.w)};
    *(uint4*)&tile[r][c8 * 8] = *(uint4*)t8;
  }
  __syncthreads();
#pragma unroll
  for (int p = 0; p < 2; ++p) {
    const int idx = p * 256 + tid;
    const int r = idx >> 3, c8 = idx & 7;
    unsigned short out[8];
#pragma unroll
    for (int j = 0; j < 8; ++j) out[j] = tile[c8 * 8 + j][r];
    *(uint4*)&WqkvT[(size_t)(n0 + r) * K + k0 + c8 * 8] = *(uint4*)out;
  }
}

// ---------------------------------------------------------------------------
// gemm_qkv: 128(M) x 384(N) tile, BK=64, 8 waves (2Mx4N, wave 64x96),
// grid 32x16 = 512 blocks. SINGLE __syncthreads() per K-tile:
//   tile T: stage A,B0,B1,B2(T+1)->nb (8 loads); read all frags from cur
//   (20 ds_read_b128); 48 MFMA; __syncthreads() (vmcnt+lgkm drain + barrier).
// Safety: cur resident via previous tile's syncthreads (drains ALL loads);
// stages->nb write a region whose last readers joined at that same barrier.
// LDS elems: A: buf*8192; B: 16384 + buf*24576 + u*8192. Total 128 KiB.
// ---------------------------------------------------------------------------

#define QSTAGE(SRC, R0, KT, LDSOFF)                                           \
  do {                                                                        \
    _Pragma("unroll") for (int p_ = 0; p_ < 2; ++p_) {                        \
      const int cb_ = w * 2 + p_;                                             \
      __builtin_amdgcn_global_load_lds(                                       \
          GAS((SRC) + (size_t)((R0) + cb_ * 8 + rl) * 2048 + (KT) + cg * 8),  \
          LAS(smem + (LDSOFF) + cb_ * 512), 16, 0, 0);                        \
    }                                                                         \
  } while (0)

#define QLDA                                                                  \
  do {                                                                        \
    _Pragma("unroll") for (int mf_ = 0; mf_ < 4; ++mf_) {                     \
      const int r_ = wm * 64 + mf_ * 16 + l15;                                \
      const unsigned short* rp_ = smem + abo + r_ * 64;                       \
      _Pragma("unroll") for (int ks_ = 0; ks_ < 2; ++ks_)                     \
        af[mf_][ks_] = *(const short8*)&rp_[((ks_ * 4 + g) ^ (r_ & 7)) * 8];  \
    }                                                                         \
  } while (0)

#define QLDB(NH, DST)                                                         \
  do {                                                                        \
    _Pragma("unroll") for (int nf_ = 0; nf_ < 2; ++nf_) {                     \
      const int r_ = wn * 96 + (NH) * 32 + nf_ * 16 + l15;                    \
      const unsigned short* rp_ = smem + 16384 + bbo + r_ * 64;               \
      _Pragma("unroll") for (int ks_ = 0; ks_ < 2; ++ks_)                     \
        DST[nf_][ks_] = *(const short8*)&rp_[((ks_ * 4 + g) ^ (r_ & 7)) * 8]; \
    }                                                                         \
  } while (0)

#define QMMA(NH, BF)                                                          \
  do {                                                                        \
    _Pragma("unroll") for (int mf_ = 0; mf_ < 4; ++mf_)                       \
    _Pragma("unroll") for (int nf_ = 0; nf_ < 2; ++nf_)                       \
    _Pragma("unroll") for (int ks_ = 0; ks_ < 2; ++ks_)                       \
      acc[mf_][(NH) * 2 + nf_] = __builtin_amdgcn_mfma_f32_16x16x32_bf16(     \
          af[mf_][ks_], BF[nf_][ks_], acc[mf_][(NH) * 2 + nf_], 0, 0, 0);     \
  } while (0)

__global__ __launch_bounds__(512, 2) void gemm_qkv_kernel(
    const unsigned short* __restrict__ A, const unsigned short* __restrict__ BT,
    const float* __restrict__ bias,
    const float* __restrict__ cosp, const float* __restrict__ sinp,
    unsigned short* __restrict__ q_ws, unsigned short* __restrict__ k_ws,
    unsigned short* __restrict__ vT_ws) {
  extern __shared__ unsigned short smem[];  // 65536 elems = 128 KiB
  const int NT = 32;

  const int tid = threadIdx.x;
  const int lane = tid & 63;
  const int w = tid >> 6;            // wave 0..7
  const int wm = w >> 2, wn = w & 3; // 2M x 4N; wave tile 64 x 96
  const int l15 = lane & 15, g = lane >> 4;
  const int rl = lane >> 3;                // staging: row within 8-row chunk
  const int cg = (lane & 7) ^ rl;          // pre-swizzled global 16B-chunk

  // bijective XCD swizzle (512 % 8 == 0)
  const int nbx = gridDim.x;               // 16 (n tiles)
  const int cpx = (nbx * gridDim.y) >> 3;
  const int orig = blockIdx.y * nbx + blockIdx.x;
  const int wgid = (orig & 7) * cpx + (orig >> 3);
  const int bx = wgid % nbx, by = wgid / nbx;
  const int m0 = by * 128, n0 = bx * 384;

  f32x4 acc[4][6];
#pragma unroll
  for (int i = 0; i < 4; ++i)
#pragma unroll
    for (int j = 0; j < 6; ++j) acc[i][j] = (f32x4){0.f, 0.f, 0.f, 0.f};

  // prologue: stage tile 0 into buf 0; syncthreads drains + joins.
  QSTAGE(A, m0, 0, 0);
  QSTAGE(BT, n0, 0, 16384);
  QSTAGE(BT, n0 + 128, 0, 24576);
  QSTAGE(BT, n0 + 256, 0, 32768);
  __syncthreads();

  short8 af[4][2], b0f[2][2], b1f[2][2], b2f[2][2];

  for (int T = 0; T < NT; ++T) {
    const int buf = T & 1, nb = buf ^ 1;
    const int abo = buf * 8192;
    const int bbo = buf * 24576;
    const int ktn = (T + 1) << 6;

    if (T + 1 < NT) {  // stage tile T+1 -> other buffer (fully dead region)
      QSTAGE(A, m0, ktn, nb * 8192);
      QSTAGE(BT, n0, ktn, 16384 + nb * 24576);
      QSTAGE(BT, n0 + 128, ktn, 24576 + nb * 24576);
      QSTAGE(BT, n0 + 256, ktn, 32768 + nb * 24576);
    }

    QLDA;
    QLDB(0, b0f);
    QLDB(1, b1f);
    QLDB(2, b2f);

    __builtin_amdgcn_s_setprio(1);
    QMMA(0, b0f);
    QMMA(1, b1f);
    QMMA(2, b2f);
    __builtin_amdgcn_s_setprio(0);

    __syncthreads();   // drains vmcnt (T+1 resident) + joins readers of cur
  }

  // ---- epilogue: bias (cols gc = n0 + wn*96 + nf*16 + l15) ----
  float bv[6];
#pragma unroll
  for (int nf = 0; nf < 6; ++nf) bv[nf] = bias[n0 + wn * 96 + nf * 16 + l15];
#pragma unroll
  for (int mi = 0; mi < 4; ++mi)
#pragma unroll
    for (int nf = 0; nf < 6; ++nf)
#pragma unroll
      for (int jj = 0; jj < 4; ++jj) acc[mi][nf][jj] += bv[nf];

  // ---- rotary: group nf has head-local idx hg=((6*wn+nf)&7); rotate pair
  //      (nf,nf+1) where hg==0, only for q/k col-blocks. Never splits a wave.
#pragma unroll
  for (int nf = 0; nf < 5; ++nf) {
    if (((6 * wn + nf) & 7) == 0) {
      const int jb = (wn * 96 + nf * 16) >> 7;          // col-block 0..2
      const int whichj = (n0 + jb * 128) >> 11;          // 0=q 1=k 2=v
      if (whichj < 2) {
#pragma unroll
        for (int mi = 0; mi < 4; ++mi)
#pragma unroll
          for (int jj = 0; jj < 4; ++jj) {
            const int t = m0 + wm * 64 + mi * 16 + g * 4 + jj;
            const float c = cosp[t * 16 + l15];
            const float s = sinp[t * 16 + l15];
            const float a1 = acc[mi][nf][jj], a2 = acc[mi][nf + 1][jj];
            acc[mi][nf][jj] = a1 * c - a2 * s;
            acc[mi][nf + 1][jj] = a1 * s + a2 * c;
          }
      }
    }
  }

  // ---- write C into 3 per-head LDS sub-tiles [128][136] (v transposed) ----
  const int b = m0 >> 10, s0v = m0 & 1023;
#pragma unroll
  for (int mi = 0; mi < 4; ++mi)
#pragma unroll
    for (int nf = 0; nf < 6; ++nf)
#pragma unroll
      for (int jj = 0; jj < 4; ++jj) {
        const int r = wm * 64 + mi * 16 + g * 4 + jj;    // token-local 0..127
        const int gc = wn * 96 + nf * 16 + l15;          // tile col 0..383
        const int jb = gc >> 7, lc = gc & 127;
        const int whichj = (n0 + jb * 128) >> 11;
        const unsigned short hv = f2b(acc[mi][nf][jj]);
        if (whichj < 2) smem[jb * 17408 + r * 136 + lc] = hv;
        else            smem[jb * 17408 + lc * 136 + r] = hv;
      }
  __syncthreads();

  // ---- flush sub-tiles, per-block q/k/v routing ----
#pragma unroll
  for (int jb = 0; jb < 3; ++jb) {
    const int gcb = n0 + jb * 128;
    const int whichj = gcb >> 11;
    const int head = (gcb >> 7) & 15;
#pragma unroll
    for (int p4 = 0; p4 < 4; ++p4) {
      const int idx = p4 * 512 + tid;
      const int rr = idx >> 4, c8 = idx & 15;
      uint4 v = *(const uint4*)&smem[jb * 17408 + rr * 136 + c8 * 8];
      unsigned short* dp;
      if (whichj == 0)
        dp = q_ws + ((size_t)(b * 16 + head) * 1024 + s0v + rr) * 128 + c8 * 8;
      else if (whichj == 1)
        dp = k_ws + ((size_t)(b * 16 + head) * 1024 + s0v + rr) * 128 + c8 * 8;
      else  // v: sub-tile row rr = head-dim d, cols = local tokens
        dp = vT_ws + ((size_t)(b * 16 + head) * 128 + rr) * 1024 + s0v + c8 * 8;
      *(uint4*)dp = v;
    }
  }
}

// ---------------------------------------------------------------------------
// gemm_out: C[4096][2048] f32 = A @ WdT^T + bias. Tile 128(M) x 256(N), BK=64,
// grid 8x32 = 256 blocks. Same minimal-sync pattern: full dbuf, stage T+1 ->
// nb, ONE __syncthreads per K-tile. LDS: A 2x8192 @0; B 2x16384 @16384 elems.
// ---------------------------------------------------------------------------

#define M1_STG(SRC, R0, KT, LB)                                               \
  __builtin_amdgcn_global_load_lds(                                           \
      GAS((SRC) + (size_t)((R0) + w * 8 + rl) * 2048 + (KT) + cg * 8),        \
      LAS(smem + (LB) + w * 512), 16, 0, 0)

#define M1_LDA                                                                \
  do {                                                                        \
    _Pragma("unroll") for (int mf_ = 0; mf_ < 4; ++mf_) {                     \
      const int r_ = wm * 64 + mf_ * 16 + l15;                                \
      const unsigned short* rp_ = smem + abo + r_ * 64;                       \
      _Pragma("unroll") for (int ks_ = 0; ks_ < 2; ++ks_)                     \
        af[mf_][ks_] = *(const short8*)&rp_[((ks_ * 4 + g) ^ (r_ & 7)) * 8];  \
    }                                                                         \
  } while (0)

#define M1_LDB(NH, DST)                                                       \
  do {                                                                        \
    _Pragma("unroll") for (int nf_ = 0; nf_ < 2; ++nf_) {                     \
      const int r_ = wn * 64 + (NH) * 32 + nf_ * 16 + l15;                    \
      const unsigned short* rp_ = smem + bbo + r_ * 64;                       \
      _Pragma("unroll") for (int ks_ = 0; ks_ < 2; ++ks_)                     \
        DST[nf_][ks_] = *(const short8*)&rp_[((ks_ * 4 + g) ^ (r_ & 7)) * 8]; \
    }                                                                         \
  } while (0)

#define M1_MMA(NH, BF)                                                        \
  do {                                                                        \
    _Pragma("unroll") for (int mf_ = 0; mf_ < 4; ++mf_)                       \
    _Pragma("unroll") for (int nf_ = 0; nf_ < 2; ++nf_)                       \
    _Pragma("unroll") for (int ks_ = 0; ks_ < 2; ++ks_)                       \
      acc[mf_][(NH) * 2 + nf_] = __builtin_amdgcn_mfma_f32_16x16x32_bf16(     \
          af[mf_][ks_], BF[nf_][ks_], acc[mf_][(NH) * 2 + nf_], 0, 0, 0);     \
  } while (0)

__global__ __launch_bounds__(512, 2) void gemm_out_kernel(
    const unsigned short* __restrict__ A, const unsigned short* __restrict__ BT,
    const float* __restrict__ bias, float* __restrict__ outp) {
  extern __shared__ unsigned short smem[];  // 49152 elems = 96 KiB
  const int NT = 32;

  const int tid = threadIdx.x;
  const int lane = tid & 63;
  const int w = tid >> 6;
  const int wm = w >> 2, wn = w & 3;   // 2M x 4N, wave out 64x64
  const int l15 = lane & 15, g = lane >> 4;
  const int rl = lane >> 3;
  const int cg = (lane & 7) ^ rl;

  // bijective XCD swizzle (256 % 8 == 0)
  const int nbx = gridDim.x;
  const int cpx = (nbx * gridDim.y) >> 3;
  const int orig = blockIdx.y * nbx + blockIdx.x;
  const int wgid = (orig & 7) * cpx + (orig >> 3);
  const int bx = wgid % nbx, by = wgid / nbx;
  const int m0 = by * 128, n0 = bx * 256;

  f32x4 acc[4][4];
#pragma unroll
  for (int i = 0; i < 4; ++i)
#pragma unroll
    for (int j = 0; j < 4; ++j) acc[i][j] = (f32x4){0.f, 0.f, 0.f, 0.f};

  // prologue: stage tile 0 -> buf 0
  M1_STG(A, m0, 0, 0);
  M1_STG(A, m0 + 64, 0, 4096);
  M1_STG(BT, n0, 0, 16384);
  M1_STG(BT, n0 + 64, 0, 16384 + 4096);
  M1_STG(BT, n0 + 128, 0, 16384 + 8192);
  M1_STG(BT, n0 + 192, 0, 16384 + 12288);
  __syncthreads();

  short8 af[4][2], c0f[2][2], c1f[2][2];

  for (int T = 0; T < NT; ++T) {
    const int buf = T & 1, nb = buf ^ 1;
    const int abo = buf * 8192;
    const int bbo = 16384 + buf * 16384;
    const int ktn = (T + 1) << 6;

    if (T + 1 < NT) {  // stage tile T+1 -> other buffer
      M1_STG(A, m0, ktn, nb * 8192);
      M1_STG(A, m0 + 64, ktn, nb * 8192 + 4096);
      M1_STG(BT, n0, ktn, 16384 + nb * 16384);
      M1_STG(BT, n0 + 64, ktn, 16384 + nb * 16384 + 4096);
      M1_STG(BT, n0 + 128, ktn, 16384 + nb * 16384 + 8192);
      M1_STG(BT, n0 + 192, ktn, 16384 + nb * 16384 + 12288);
    }

    M1_LDA;
    M1_LDB(0, c0f);
    M1_LDB(1, c1f);

    __builtin_amdgcn_s_setprio(1);
    M1_MMA(0, c0f);
    M1_MMA(1, c1f);
    __builtin_amdgcn_s_setprio(0);

    __syncthreads();
  }

  // ---- epilogue: bias + f32 store ----
  float bv[4];
#pragma unroll
  for (int nf = 0; nf < 4; ++nf) bv[nf] = bias[n0 + wn * 64 + nf * 16 + l15];
#pragma unroll
  for (int mi = 0; mi < 4; ++mi)
#pragma unroll
    for (int nf = 0; nf < 4; ++nf)
#pragma unroll
      for (int jj = 0; jj < 4; ++jj) {
        const int r = wm * 64 + mi * 16 + g * 4 + jj;
        const int c = wn * 64 + nf * 16 + l15;
        outp[(size_t)(m0 + r) * 2048 + n0 + c] = acc[mi][nf][jj] + bv[nf];
      }
}

// ---------------------------------------------------------------------------
// attn + Wd-transpose fused (R9-proven, unchanged). Blocks [0,1024): causal
// flash attention (K,V staged via global_load_lds, XOR-swizzled, dbuf, 1
// barrier/tile, T5 setprio). Blocks [1024,2048): Wd -> WdT transpose.
// ---------------------------------------------------------------------------
__global__ __launch_bounds__(256) void attn_kernel(
    const unsigned short* __restrict__ q_ws, const unsigned short* __restrict__ k_ws,
    const unsigned short* __restrict__ vT_ws, unsigned short* __restrict__ attn_ws,
    const float* __restrict__ Wd, unsigned short* __restrict__ WdT) {
  __shared__ __align__(16) unsigned short Ksl[2][8192];  // [kv 64][d 128] swizzled
  __shared__ __align__(16) unsigned short Vsl[2][8192];  // [d 128][kv 64] swizzled
  __shared__ __align__(16) unsigned short Psl[64 * 72];  // [q 64][kv 64+8]

  const int tid = threadIdx.x;

  if (blockIdx.x >= 1024) {  // ---- Wd transpose path (reuses Ksl as tile) ----
    unsigned short (*tile)[72] = reinterpret_cast<unsigned short(*)[72]>(&Ksl[0][0]);
    const int bid = blockIdx.x - 1024;        // 0..1023
    const int n0 = (bid & 31) * 64, k0 = (bid >> 5) * 64;
    const int K = 2048, N = 2048;
#pragma unroll
    for (int p = 0; p < 2; ++p) {
      const int idx = p * 256 + tid;
      const int r = idx >> 3, c8 = idx & 7;
      const float* sp = &Wd[(size_t)(k0 + r) * N + n0 + c8 * 8];
      float4 v0 = *(const float4*)sp;
      float4 v1 = *(const float4*)(sp + 4);
      unsigned short t8[8] = {f2b(v0.x), f2b(v0.y), f2b(v0.z), f2b(v0.w),
                              f2b(v1.x), f2b(v1.y), f2b(v1.z), f2b(v1.w)};
      *(uint4*)&tile[r][c8 * 8] = *(uint4*)t8;
    }
    __syncthreads();
#pragma unroll
    for (int p = 0; p < 2; ++p) {
      const int idx = p * 256 + tid;
      const int r = idx >> 3, c8 = idx & 7;
      unsigned short out[8];
#pragma unroll
      for (int j = 0; j < 8; ++j) out[j] = tile[c8 * 8 + j][r];
      *(uint4*)&WdT[(size_t)(n0 + r) * K + k0 + c8 * 8] = *(uint4*)out;
    }
    return;
  }

  // ---- attention path ----
  const int lane = tid & 63;
  const int w = tid >> 6;
  const int l15 = lane & 15, g = lane >> 4;

  const int lid = blockIdx.x;                 // 0..1023
  const int bh  = (lid & 7) + 8 * ((lid >> 3) & 7);   // same bh -> same XCD
  const int qt  = 15 - (lid >> 6);            // big q-tiles dispatch first
  const int q0  = qt * 64;
  const size_t qkb = (size_t)bh * 131072;     // 1024*128
  const unsigned short* kg = k_ws + qkb;
  const unsigned short* vg = vT_ws + qkb;

  short8 qf[4];
#pragma unroll
  for (int ks = 0; ks < 4; ++ks)
    qf[ks] = *(const short8*)&q_ws[qkb + (size_t)(q0 + w * 16 + l15) * 128 + ks * 32 + g * 8];

  f32x4 o[8];
#pragma unroll
  for (int j = 0; j < 8; ++j) o[j] = (f32x4){0.f, 0.f, 0.f, 0.f};
  float lsum[4] = {0.f, 0.f, 0.f, 0.f};

  const float CS = 0.08838834764831845f * 1.4426950408889634f;  // scale*log2e
  const int ntiles = qt + 1;

#pragma unroll
  for (int p = 0; p < 4; ++p) {
    const int base = (w * 4 + p) * 64;        // chunk base (wave-uniform)
    {
      const int L = base + lane, r = L >> 4, s = L & 15;
      const int c = (s & 8) | ((s ^ r) & 7);
      __builtin_amdgcn_global_load_lds(GAS(kg + r * 128 + c * 8),
                                       LAS(&Ksl[0][base * 8]), 16, 0, 0);
    }
    {
      const int L = base + lane, r = L >> 3, s = L & 7;
      const int c = (s ^ r) & 7;
      __builtin_amdgcn_global_load_lds(GAS(vg + (size_t)r * 1024 + c * 8),
                                       LAS(&Vsl[0][base * 8]), 16, 0, 0);
    }
  }

  int buf = 0;
  for (int jt = 0; jt < ntiles; ++jt) {
    __syncthreads();   // tile jt staged; previous buf's readers done

    if (jt + 1 < ntiles) {  // async prefetch jt+1 -> other buf
      const unsigned short* kb = kg + (size_t)(jt + 1) * 8192;
      const unsigned short* vb = vg + (jt + 1) * 64;
      const int nb = buf ^ 1;
#pragma unroll
      for (int p = 0; p < 4; ++p) {
        const int base = (w * 4 + p) * 64;
        {
          const int L = base + lane, r = L >> 4, s = L & 15;
          const int c = (s & 8) | ((s ^ r) & 7);
          __builtin_amdgcn_global_load_lds(GAS(kb + r * 128 + c * 8),
                                           LAS(&Ksl[nb][base * 8]), 16, 0, 0);
        }
        {
          const int L = base + lane, r = L >> 3, s = L & 7;
          const int c = (s ^ r) & 7;
          __builtin_amdgcn_global_load_lds(GAS(vb + (size_t)r * 1024 + c * 8),
                                           LAS(&Vsl[nb][base * 8]), 16, 0, 0);
        }
      }
    }

    f32x4 s[4];
#pragma unroll
    for (int nf = 0; nf < 4; ++nf) s[nf] = (f32x4){0.f, 0.f, 0.f, 0.f};
    __builtin_amdgcn_s_setprio(1);
#pragma unroll
    for (int nf = 0; nf < 4; ++nf) {
      const int r = nf * 16 + l15;
#pragma unroll
      for (int ks = 0; ks < 4; ++ks) {
        const int c = ks * 4 + g;
        const int sl = (c & 8) | ((c ^ r) & 7);
        short8 bfrk = *(const short8*)&Ksl[buf][r * 128 + sl * 8];
        s[nf] = __builtin_amdgcn_mfma_f32_16x16x32_bf16(qf[ks], bfrk, s[nf], 0, 0, 0);
      }
    }
    __builtin_amdgcn_s_setprio(0);

    const bool diag = (jt == ntiles - 1);
#pragma unroll
    for (int jj = 0; jj < 4; ++jj) {
      float pv[4];
      if (diag) {
        const int rloc = w * 16 + g * 4 + jj;   // kv0 == q0 on diagonal
#pragma unroll
        for (int nf = 0; nf < 4; ++nf)
          pv[nf] = (nf * 16 + l15 > rloc) ? 0.f
                 : __builtin_amdgcn_exp2f(s[nf][jj] * CS);
      } else {
#pragma unroll
        for (int nf = 0; nf < 4; ++nf)
          pv[nf] = __builtin_amdgcn_exp2f(s[nf][jj] * CS);
      }
      lsum[jj] += (pv[0] + pv[1]) + (pv[2] + pv[3]);
#pragma unroll
      for (int nf = 0; nf < 4; ++nf)
        Psl[(w * 16 + g * 4 + jj) * 72 + nf * 16 + l15] = f2b(pv[nf]);
    }

    __builtin_amdgcn_s_setprio(1);
#pragma unroll
    for (int ks = 0; ks < 2; ++ks) {
      short8 a0 = *(const short8*)&Psl[(w * 16 + l15) * 72 + ks * 32 + g * 8];
#pragma unroll
      for (int nd = 0; nd < 8; ++nd) {
        const int r = nd * 16 + l15;
        const int c = ks * 4 + g;
        const int sl = (c ^ r) & 7;
        short8 bfrv = *(const short8*)&Vsl[buf][r * 64 + sl * 8];
        o[nd] = __builtin_amdgcn_mfma_f32_16x16x32_bf16(a0, bfrv, o[nd], 0, 0, 0);
      }
    }
    __builtin_amdgcn_s_setprio(0);
    buf ^= 1;
  }

#pragma unroll
  for (int jj = 0; jj < 4; ++jj) {
    float rs = lsum[jj];
    rs += __shfl_xor(rs, 1);
    rs += __shfl_xor(rs, 2);
    rs += __shfl_xor(rs, 4);
    rs += __shfl_xor(rs, 8);
    const float inv = 1.f / rs;
    const int t = (bh >> 4) * 1024 + q0 + w * 16 + g * 4 + jj;
    unsigned short* dst = attn_ws + (size_t)t * 2048 + (bh & 15) * 128;
#pragma unroll
    for (int nd = 0; nd < 8; ++nd)
      dst[nd * 16 + l15] = f2b(o[nd][jj] * inv);
  }
}

// ---------------------------------------------------------------------------
extern "C" void kernel_launch(void* const* d_in, const int* in_sizes, int n_in,
                              void* d_out, int out_size, void* d_ws, size_t ws_size,
                              hipStream_t stream) {
  const float* hidden = (const float*)d_in[0];
  const float* cosp   = (const float*)d_in[1];
  const float* sinp   = (const float*)d_in[2];
  const float* Wqkv   = (const float*)d_in[3];
  const float* bqkv   = (const float*)d_in[4];
  const float* Wd     = (const float*)d_in[5];
  const float* bd     = (const float*)d_in[6];

  // ws layout (bf16 elems), aliased:
  //   [0, 8.39M)       hidden_bf  -> (dead after gemm_qkv) attn_bf
  //   [8.39M, 20.97M)  WqkvT      -> (dead after gemm_qkv) WdT
  //   [20.97M, ...)    q_ws, k_ws, vT_ws (8.39M each)
  unsigned short* ws        = (unsigned short*)d_ws;
  unsigned short* hidden_bf = ws;
  unsigned short* attn_bf   = ws;
  unsigned short* WqkvT     = ws + 8388608;
  unsigned short* WdT       = ws + 8388608;
  unsigned short* q_ws      = ws + 20971520;
  unsigned short* k_ws      = q_ws + 8388608;
  unsigned short* vT_ws     = k_ws + 8388608;

  static bool attr_inited = false;
  if (!attr_inited) {
    hipFuncSetAttribute(reinterpret_cast<const void*>(gemm_qkv_kernel),
                        hipFuncAttributeMaxDynamicSharedMemorySize, 131072);
    hipFuncSetAttribute(reinterpret_cast<const void*>(gemm_out_kernel),
                        hipFuncAttributeMaxDynamicSharedMemorySize, 98304);
    attr_inited = true;
  }

  pre_kernel<<<7168, 256, 0, stream>>>(hidden, hidden_bf, Wqkv, WqkvT);
  gemm_qkv_kernel<<<dim3(16, 32), 512, 131072, stream>>>(
      hidden_bf, WqkvT, bqkv, cosp, sinp, q_ws, k_ws, vT_ws);
  attn_kernel<<<2048, 256, 0, stream>>>(q_ws, k_ws, vT_ws, attn_bf, Wd, WdT);
  gemm_out_kernel<<<dim3(8, 32), 512, 98304, stream>>>(
      attn_bf, WdT, bd, (float*)d_out);
}